// Round 23
// baseline (372.406 us; speedup 1.0000x reference)
//
#include <hip/hip_runtime.h>
#include <hip/hip_bf16.h>
#include <stdint.h>

#define NND 3072
#define NB8 (NND / 8)      // adjbits row bytes = 384
#define DD 300
#define HH 4
#define F2 1200
#define TNC 40             // ccgemm/ygemm LDS pad (32 + 8)
#define MREP 5             // fatt feature sub-tiles per wave (80 features)
#define PANEL (MREP * 16)
#define KQ (NND / 4)       // per-wave K-quarter (768)
#define APAD 320           // padded feature rows of Z buffers
#define AS ((size_t)APAD * NND)   // elements per Z slot
#define LOG2E 1.4426950408889634f

typedef __attribute__((ext_vector_type(8))) short short8v;
typedef __attribute__((ext_vector_type(4))) float f32x4;
typedef __hip_bfloat16 bf16;

__device__ inline float ldin(const void* p, size_t i, int isf32) {
    return isf32 ? ((const float*)p)[i]
                 : __bfloat162float(((const bf16*)p)[i]);
}

__device__ inline ushort f2bf(float x) {
    bf16 t = __float2bfloat16(x);
    return *reinterpret_cast<ushort*>(&t);
}

__device__ inline uint pack2(float lo, float hi) {
    return (uint)f2bf(lo) | ((uint)f2bf(hi) << 16);
}

// ---- dtype sniffer: flags[0]=1 iff float inputs are f32; flags[1]=1 iff adj is int32
__global__ void k_detect(const void* emb, const void* adj, int* flags) {
    if (threadIdx.x == 0 && blockIdx.x == 0) {
        const uint16_t* u = (const uint16_t*)emb;
        int plaus = 0;
        for (int i = 0; i < 128; i++) {
            int e = (u[i] >> 7) & 0xFF;
            if (e >= 112 && e <= 143) plaus++;
        }
        flags[0] = (plaus < 100) ? 1 : 0;
        const uint8_t* b = (const uint8_t*)adj;
        int nz = 0;
        for (int i = 0; i < 256; i++) if ((i & 3) != 0 && b[i]) nz++;
        flags[1] = (nz == 0) ? 1 : 0;
    }
}

// ---- pack adjacency to 1 bit per entry: adjbits[i][j/8]
__global__ void k_adjpack(const void* adj, const int* flags, uint8_t* bits) {
    int i = blockIdx.x, o = threadIdx.x;
    int adjInt = flags[1];
    uint8_t b = 0;
    if (!adjInt) {
        const uint8_t* row = (const uint8_t*)adj + (size_t)i * NND + o * 8;
        uint2 v = *(const uint2*)row;
        #pragma unroll
        for (int jj = 0; jj < 4; jj++) {
            if ((v.x >> (8 * jj)) & 0xffu) b |= 1u << jj;
            if ((v.y >> (8 * jj)) & 0xffu) b |= 1u << (4 + jj);
        }
    } else {
        const int* row = (const int*)adj + (size_t)i * NND + o * 8;
        int4 u = *(const int4*)row;
        int4 v = *(const int4*)(row + 4);
        if (u.x) b |= 1;  if (u.y) b |= 2;   if (u.z) b |= 4;   if (u.w) b |= 8;
        if (v.x) b |= 16; if (v.y) b |= 32;  if (v.z) b |= 64;  if (v.w) b |= 128;
    }
    bits[(size_t)i * NB8 + o] = b;
}

// ---- T[c][r] = A[r][c], output bf16.  grid = ((C+31)/32, (R+31)/32)
__global__ void k_transpose(const void* A, size_t baseOff, bf16* T, int R, int C,
                            const int* flags, int useFlag) {
    __shared__ bf16 t[32][33];
    int isf = useFlag ? flags[0] : 0;
    int rt = blockIdx.y * 32, ct = blockIdx.x * 32;
    int tx = threadIdx.x, ty = threadIdx.y;
    for (int i = 0; i < 4; i++) {
        int r = rt + ty + 8 * i, c = ct + tx;
        if (r < R && c < C)
            t[ty + 8 * i][tx] = __float2bfloat16(ldin(A, baseOff + (size_t)r * C + c, isf));
    }
    __syncthreads();
    for (int i = 0; i < 4; i++) {
        int c = ct + ty + 8 * i, r = rt + tx;
        if (c < C && r < R) T[(size_t)c * R + r] = t[tx][ty + 8 * i];
    }
}

// ---- u1 = LOG2E * (W @ a[:C]), u2 = LOG2E * (W @ a[C:2C])
// (log2e folded in so the fatt hot loops use bare exp2 -> v_exp_f32;
//  leaky_relu commutes with the positive scale)
__global__ void k_uvec(const void* W, const void* a, float* u1, float* u2, int R, int C,
                       long Wb, long ab, long ub, const int* flags) {
    int isf = flags[0];
    int h = blockIdx.y;
    int wid = threadIdx.x >> 6, lane = threadIdx.x & 63;
    int r = blockIdx.x * 4 + wid;
    if (r >= R) return;
    float s1 = 0.f, s2 = 0.f;
    for (int c = lane; c < C; c += 64) {
        float w = ldin(W, (size_t)h * Wb + (size_t)r * C + c, isf);
        s1 += w * ldin(a, (size_t)h * ab + c, isf);
        s2 += w * ldin(a, (size_t)h * ab + C + c, isf);
    }
    for (int o = 32; o; o >>= 1) { s1 += __shfl_down(s1, o); s2 += __shfl_down(s2, o); }
    if (lane == 0) { u1[(size_t)h * ub + r] = s1 * LOG2E; u2[(size_t)h * ub + r] = s2 * LOG2E; }
}

// ---- o1[i] = X[i,:]·u1, o2[i] = X[i,:]·u2
__global__ void k_gemv2(const void* X, const float* u1, const float* u2, float* o1, float* o2,
                        int M, int K, long ub, long ob, const int* flags, int useFlag) {
    int isf = useFlag ? flags[0] : 0;
    int h = blockIdx.y;
    const float* U1 = u1 + (size_t)h * ub;
    const float* U2 = u2 + (size_t)h * ub;
    int wid = threadIdx.x >> 6, lane = threadIdx.x & 63;
    int row = blockIdx.x * 4 + wid;
    if (row >= M) return;
    float s1 = 0.f, s2 = 0.f;
    for (int k = lane; k < K; k += 64) {
        float x = ldin(X, (size_t)row * K + k, isf);
        s1 += x * U1[k]; s2 += x * U2[k];
    }
    for (int o = 32; o; o >>= 1) { s1 += __shfl_down(s1, o); s2 += __shfl_down(s2, o); }
    if (lane == 0) { o1[(size_t)h * ob + row] = s1; o2[(size_t)h * ob + row] = s2; }
}

// ---- fused attention GEMM, fat i-tile (IBLK=48, R22-proven): 5 A-loads feed
// 30 MFMAs per k-step. acc[5][3][2]=120 AGPR. Scores pre-scaled by log2e ->
// bare exp2. Single A operand (Xt, L2-resident). K-split x4 in-block.
__global__ __launch_bounds__(256, 2) void k_fatt2(
    const float* __restrict__ Wh1A, const float* __restrict__ Wh2A, long hs,
    const uint8_t* __restrict__ adjbits,
    const bf16* __restrict__ Xt,           // [rowsPad][NND] feature-major, zero-padded
    bf16* __restrict__ CC, long ccHeadStride, int ccStride, int F) {
    __shared__ float lmerge[126][64];      // 120 acc + 6 sums, idx-major (conflict-free)
    int h = blockIdx.z;
    const float* Wh1 = Wh1A + (size_t)h * hs;
    const float* Wh2 = Wh2A + (size_t)h * hs;
    bf16* C = CC + (size_t)h * ccHeadStride;
    int w = threadIdx.x >> 6, lane = threadIdx.x & 63;
    int fbase = blockIdx.y * PANEL;
    int ibase = blockIdx.x * 48;
    int li = lane & 15;
    int ksh = (lane >> 4) * 8;             // k-octet offset within 32-k step
    float w1v[3];
    const uint8_t* abv[3];
    #pragma unroll
    for (int t = 0; t < 3; t++) {
        w1v[t] = Wh1[ibase + t * 16 + li];
        abv[t] = adjbits + (size_t)(ibase + t * 16 + li) * NB8;
    }
    const bf16* Abase = Xt + (size_t)(fbase + li) * NND + ksh;
    f32x4 acc[MREP][3][2] = {};            // [m][itile][side]
    float sp[3] = {0.f, 0.f, 0.f}, sn[3] = {0.f, 0.f, 0.f};

    int kbeg = w * KQ;
    for (int k0 = kbeg; k0 < kbeg + KQ; k0 += 32) {
        float4 wa = *(const float4*)(Wh2 + k0 + ksh);
        float4 wb = *(const float4*)(Wh2 + k0 + ksh + 4);
        float zs0 = wa.x, zs1 = wa.y, zs2 = wa.z, zs3 = wa.w;
        float zs4 = wb.x, zs5 = wb.y, zs6 = wb.z, zs7 = wb.w;
        short8v bp[3], bq[3];
        #pragma unroll
        for (int t = 0; t < 3; t++) {
            uint m1 = *(const uint*)(abv[t] + (k0 >> 3));
            #pragma unroll
            for (int jj = 0; jj < 8; jj++) {
                float zj = (jj == 0) ? zs0 : (jj == 1) ? zs1 : (jj == 2) ? zs2 : (jj == 3) ? zs3
                         : (jj == 4) ? zs4 : (jj == 5) ? zs5 : (jj == 6) ? zs6 : zs7;
                bool on = (m1 >> (ksh + jj)) & 1u;
                float z1 = w1v[t] + zj;
                float e1 = fmaxf(z1, 0.3f * z1);   // leaky_relu(0.3), log2 scale
                float pe = on ? exp2f(e1) : 0.0f;
                float qe = on ? exp2f(-e1) : 0.0f;
                sp[t] += pe; sn[t] += qe;
                bp[t][jj] = (short)f2bf(pe); bq[t][jj] = (short)f2bf(qe);
            }
        }
        #pragma unroll
        for (int m = 0; m < MREP; m++) {
            short8v a = *(const short8v*)(Abase + (size_t)m * 16 * NND + k0);
            #pragma unroll
            for (int t = 0; t < 3; t++) {
                acc[m][t][0] = __builtin_amdgcn_mfma_f32_16x16x32_bf16(a, bp[t], acc[m][t][0], 0, 0, 0);
                acc[m][t][1] = __builtin_amdgcn_mfma_f32_16x16x32_bf16(a, bq[t], acc[m][t][1], 0, 0, 0);
            }
        }
    }

    // ---- K-quarter merge: waves 1..3 deposit in turn; wave0 accumulates.
    #pragma unroll
    for (int tt = 1; tt < 4; tt++) {
        if (w == tt) {
            #pragma unroll
            for (int m = 0; m < MREP; m++)
                #pragma unroll
                for (int t = 0; t < 3; t++)
                    #pragma unroll
                    for (int s = 0; s < 2; s++)
                        #pragma unroll
                        for (int r = 0; r < 4; r++)
                            lmerge[((m * 3 + t) * 2 + s) * 4 + r][lane] = acc[m][t][s][r];
            #pragma unroll
            for (int t = 0; t < 3; t++) {
                lmerge[120 + t][lane] = sp[t];
                lmerge[123 + t][lane] = sn[t];
            }
        }
        __syncthreads();
        if (w == 0) {
            #pragma unroll
            for (int m = 0; m < MREP; m++)
                #pragma unroll
                for (int t = 0; t < 3; t++)
                    #pragma unroll
                    for (int s = 0; s < 2; s++)
                        #pragma unroll
                        for (int r = 0; r < 4; r++)
                            acc[m][t][s][r] += lmerge[((m * 3 + t) * 2 + s) * 4 + r][lane];
            #pragma unroll
            for (int t = 0; t < 3; t++) {
                sp[t] += lmerge[120 + t][lane];
                sn[t] += lmerge[123 + t][lane];
            }
        }
        __syncthreads();
    }
    if (w != 0) return;

    #pragma unroll
    for (int t = 0; t < 3; t++) {
        sp[t] += __shfl_xor(sp[t], 16); sp[t] += __shfl_xor(sp[t], 32);
        sn[t] += __shfl_xor(sn[t], 16); sn[t] += __shfl_xor(sn[t], 32);
    }
    int fo = (lane >> 4) * 4;
    #pragma unroll
    for (int t = 0; t < 3; t++) {
        float sc[2] = { 1.0f / sp[t], -1.0f / sn[t] };
        bf16* crow = C + (size_t)(ibase + t * 16 + li) * ccStride;
        #pragma unroll
        for (int m = 0; m < MREP; m++) {
            int fc = fbase + m * 16 + fo;
            if (fc >= F) continue;
            #pragma unroll
            for (int side = 0; side < 2; side++) {
                uint2 uv;
                uv.x = pack2(acc[m][t][side][0] * sc[side], acc[m][t][side][1] * sc[side]);
                uv.y = pack2(acc[m][t][side][2] * sc[side], acc[m][t][side][3] * sc[side]);
                *(uint2*)(crow + side * F + fc) = uv;
            }
        }
    }
}

// ---- Out[:,off:off+N] = epi(A @ Bt^T); M-tile 32, N-tile 64; head-batched via blockIdx.z
__global__ __launch_bounds__(256) void k_ccgemm(const bf16* __restrict__ A0, const bf16* __restrict__ Bt0,
                                                bf16* __restrict__ Out, int K, int Ncols,
                                                int outStride, int outColOff0, int mode,
                                                long aHeadStride, long btHeadStride, int outColStep) {
    __shared__ __align__(16) bf16 Alds[32 * TNC];
    __shared__ __align__(16) bf16 Blds[64 * TNC];
    int h = blockIdx.z;
    const bf16* A = A0 + (size_t)h * aHeadStride;
    const bf16* Bt = Bt0 + (size_t)h * btHeadStride;
    int outColOff = outColOff0 + h * outColStep;
    int tid = threadIdx.x, lane = tid & 63, w = tid >> 6, wr = w >> 1, wc = w & 1;
    int m0 = blockIdx.y * 32, n0 = blockIdx.x * 64;
    int smA = tid >> 3, skA = (tid & 7) * 4;
    int smB = tid >> 2, skB = (tid & 3) * 8;
    f32x4 acc[2] = {};
    for (int k0 = 0; k0 < K; k0 += 32) {
        uint2 va = make_uint2(0, 0);
        uint4 vx = make_uint4(0, 0, 0, 0);
        if (k0 + skA < K) va = *(const uint2*)(A + (size_t)(m0 + smA) * K + k0 + skA);
        if (n0 + smB < Ncols && k0 + skB < K) vx = *(const uint4*)(Bt + (size_t)(n0 + smB) * K + k0 + skB);
        __syncthreads();
        *(uint2*)&Alds[smA * TNC + skA] = va;
        *(uint4*)&Blds[smB * TNC + skB] = vx;
        __syncthreads();
        int arr = wr * 16 + (lane & 15), koff = (lane >> 4) * 8;
        int br = wc * 32 + (lane & 15);
        short8v a0 = *(const short8v*)&Alds[arr * TNC + koff];
        short8v b0 = *(const short8v*)&Blds[br * TNC + koff];
        short8v b1 = *(const short8v*)&Blds[(br + 16) * TNC + koff];
        acc[0] = __builtin_amdgcn_mfma_f32_16x16x32_bf16(a0, b0, acc[0], 0, 0, 0);
        acc[1] = __builtin_amdgcn_mfma_f32_16x16x32_bf16(a0, b1, acc[1], 0, 0, 0);
    }
    for (int ni = 0; ni < 2; ni++) {
        int col = n0 + wc * 32 + ni * 16 + (lane & 15);
        if (col >= Ncols) continue;
        int rbase = m0 + wr * 16 + (lane >> 4) * 4;
        for (int r = 0; r < 4; r++) {
            float v = acc[ni][r];
            if (mode == 0) v = v > 0.f ? v : (__expf(v) - 1.0f);
            else           v = 1.0f / (1.0f + __expf(-v));
            Out[(size_t)(rbase + r) * outStride + outColOff + col] = __float2bfloat16(v);
        }
    }
}

// ---- Zt builder: Out[z][f][i] = sum_k Wt[f][z*coffStep + k] * Bt[i][k]
__global__ __launch_bounds__(256) void k_ygemm(
    const bf16* __restrict__ A0, long aHeadStride, int coffStep, int lda,
    const bf16* __restrict__ Bt, int K,
    bf16* __restrict__ Out0) {
    __shared__ __align__(16) bf16 Alds[32 * TNC];
    __shared__ __align__(16) bf16 Blds[64 * TNC];
    int z = blockIdx.z;
    const bf16* A = A0 + (size_t)(z >> 1) * aHeadStride;
    int coff = (z & 1) * coffStep;
    bf16* Out = Out0 + (size_t)z * AS;
    int tid = threadIdx.x, lane = tid & 63, w = tid >> 6, wr = w >> 1, wc = w & 1;
    int m0 = blockIdx.y * 32, n0 = blockIdx.x * 64;
    int smA = tid >> 3, skA = (tid & 7) * 4;
    int smB = tid >> 2, skB = (tid & 3) * 8;
    f32x4 acc[2] = {};
    for (int k0 = 0; k0 < K; k0 += 32) {
        uint2 va = make_uint2(0, 0);
        uint4 vx = make_uint4(0, 0, 0, 0);
        if (m0 + smA < DD && k0 + skA < K)
            va = *(const uint2*)(A + (size_t)(m0 + smA) * lda + coff + k0 + skA);
        if (k0 + skB < K)
            vx = *(const uint4*)(Bt + (size_t)(n0 + smB) * K + k0 + skB);
        __syncthreads();
        *(uint2*)&Alds[smA * TNC + skA] = va;
        *(uint4*)&Blds[smB * TNC + skB] = vx;
        __syncthreads();
        int arr = wr * 16 + (lane & 15), koff = (lane >> 4) * 8;
        int br = wc * 32 + (lane & 15);
        short8v a0 = *(const short8v*)&Alds[arr * TNC + koff];
        short8v b0 = *(const short8v*)&Blds[br * TNC + koff];
        short8v b1 = *(const short8v*)&Blds[(br + 16) * TNC + koff];
        acc[0] = __builtin_amdgcn_mfma_f32_16x16x32_bf16(a0, b0, acc[0], 0, 0, 0);
        acc[1] = __builtin_amdgcn_mfma_f32_16x16x32_bf16(a0, b1, acc[1], 0, 0, 0);
    }
    for (int ni = 0; ni < 2; ni++) {
        int col = n0 + wc * 32 + ni * 16 + (lane & 15);
        int rbase = m0 + wr * 16 + (lane >> 4) * 4;
        for (int r = 0; r < 4; r++) {
            if (rbase + r < DD)
                Out[(size_t)(rbase + r) * NND + col] = __float2bfloat16(acc[ni][r]);
        }
    }
}

// ---- fused signed attention + projection, fat i-tile (IBLK=48): dual-A,
// 10 A-loads feed 30 MFMAs per k-step (ratio 3, was 2). acc[5][3][2]=120 AGPR.
// Out[i][f] = sigmoid( rsp*Pp@Zp + rsn*Pn@Zn ). Scores in log2 scale -> exp2.
__global__ __launch_bounds__(256, 2) void k_fatt7(
    const float* __restrict__ Wh1A, const float* __restrict__ Wh2A, long hs,
    const uint8_t* __restrict__ adjbits,
    const bf16* __restrict__ Aall,
    bf16* __restrict__ Out, int ostride, int ocolStep, int mode) {
    __shared__ float lmerge[126][64];
    int slot = blockIdx.z;
    const float* Wh1 = Wh1A + (size_t)slot * hs;
    const float* Wh2 = Wh2A + (size_t)slot * hs;
    const bf16* Ap = Aall + (size_t)slot * 2 * AS;
    const bf16* An = Ap + AS;
    int ocol = slot * ocolStep;
    int w = threadIdx.x >> 6, lane = threadIdx.x & 63;
    int fbase = blockIdx.y * PANEL;
    int ibase = blockIdx.x * 48;
    int li = lane & 15;
    int ksh = (lane >> 4) * 8;
    float w1v[3];
    const uint8_t* abv[3];
    #pragma unroll
    for (int t = 0; t < 3; t++) {
        w1v[t] = Wh1[ibase + t * 16 + li];
        abv[t] = adjbits + (size_t)(ibase + t * 16 + li) * NB8;
    }
    size_t aoff = (size_t)(fbase + li) * NND + ksh;
    const bf16* Abp = Ap + aoff;
    const bf16* Abn = An + aoff;
    f32x4 acc[MREP][3][2] = {};            // [m][itile][chain p/n]
    float sp[3] = {0.f, 0.f, 0.f}, sn[3] = {0.f, 0.f, 0.f};

    int kbeg = w * KQ;
    for (int k0 = kbeg; k0 < kbeg + KQ; k0 += 32) {
        float4 wa = *(const float4*)(Wh2 + k0 + ksh);
        float4 wb = *(const float4*)(Wh2 + k0 + ksh + 4);
        float zs0 = wa.x, zs1 = wa.y, zs2 = wa.z, zs3 = wa.w;
        float zs4 = wb.x, zs5 = wb.y, zs6 = wb.z, zs7 = wb.w;
        short8v bp[3], bq[3];
        #pragma unroll
        for (int t = 0; t < 3; t++) {
            uint m1 = *(const uint*)(abv[t] + (k0 >> 3));
            #pragma unroll
            for (int jj = 0; jj < 8; jj++) {
                float zj = (jj == 0) ? zs0 : (jj == 1) ? zs1 : (jj == 2) ? zs2 : (jj == 3) ? zs3
                         : (jj == 4) ? zs4 : (jj == 5) ? zs5 : (jj == 6) ? zs6 : zs7;
                bool on = (m1 >> (ksh + jj)) & 1u;
                float z1 = w1v[t] + zj;
                float e1 = fmaxf(z1, 0.3f * z1);
                float pe = on ? exp2f(e1) : 0.0f;
                float qe = on ? exp2f(-e1) : 0.0f;
                sp[t] += pe; sn[t] += qe;
                bp[t][jj] = (short)f2bf(pe); bq[t][jj] = (short)f2bf(qe);
            }
        }
        #pragma unroll
        for (int m = 0; m < MREP; m++) {
            short8v ap = *(const short8v*)(Abp + (size_t)m * 16 * NND + k0);
            short8v an = *(const short8v*)(Abn + (size_t)m * 16 * NND + k0);
            #pragma unroll
            for (int t = 0; t < 3; t++) {
                acc[m][t][0] = __builtin_amdgcn_mfma_f32_16x16x32_bf16(ap, bp[t], acc[m][t][0], 0, 0, 0);
                acc[m][t][1] = __builtin_amdgcn_mfma_f32_16x16x32_bf16(an, bq[t], acc[m][t][1], 0, 0, 0);
            }
        }
    }

    #pragma unroll
    for (int tt = 1; tt < 4; tt++) {
        if (w == tt) {
            #pragma unroll
            for (int m = 0; m < MREP; m++)
                #pragma unroll
                for (int t = 0; t < 3; t++)
                    #pragma unroll
                    for (int s = 0; s < 2; s++)
                        #pragma unroll
                        for (int r = 0; r < 4; r++)
                            lmerge[((m * 3 + t) * 2 + s) * 4 + r][lane] = acc[m][t][s][r];
            #pragma unroll
            for (int t = 0; t < 3; t++) {
                lmerge[120 + t][lane] = sp[t];
                lmerge[123 + t][lane] = sn[t];
            }
        }
        __syncthreads();
        if (w == 0) {
            #pragma unroll
            for (int m = 0; m < MREP; m++)
                #pragma unroll
                for (int t = 0; t < 3; t++)
                    #pragma unroll
                    for (int s = 0; s < 2; s++)
                        #pragma unroll
                        for (int r = 0; r < 4; r++)
                            acc[m][t][s][r] += lmerge[((m * 3 + t) * 2 + s) * 4 + r][lane];
            #pragma unroll
            for (int t = 0; t < 3; t++) {
                sp[t] += lmerge[120 + t][lane];
                sn[t] += lmerge[123 + t][lane];
            }
        }
        __syncthreads();
    }
    if (w != 0) return;

    #pragma unroll
    for (int t = 0; t < 3; t++) {
        sp[t] += __shfl_xor(sp[t], 16); sp[t] += __shfl_xor(sp[t], 32);
        sn[t] += __shfl_xor(sn[t], 16); sn[t] += __shfl_xor(sn[t], 32);
    }
    int fo = (lane >> 4) * 4;
    #pragma unroll
    for (int t = 0; t < 3; t++) {
        float rp = 1.0f / sp[t], rn = -1.0f / sn[t];
        bf16* crow = Out + (size_t)(ibase + t * 16 + li) * ostride + ocol;
        #pragma unroll
        for (int m = 0; m < MREP; m++) {
            int fc = fbase + m * 16 + fo;
            if (fc >= DD) continue;
            float v1[4];
            #pragma unroll
            for (int r = 0; r < 4; r++) {
                float a = acc[m][t][0][r] * rp + acc[m][t][1][r] * rn;
                if (mode == 0) a = a > 0.f ? a : (__expf(a) - 1.0f);
                else           a = 1.0f / (1.0f + __expf(-a));
                v1[r] = a;
            }
            uint2 uv;
            uv.x = pack2(v1[0], v1[1]); uv.y = pack2(v1[2], v1[3]);
            *(uint2*)(crow + fc) = uv;
        }
    }
}

__global__ void k_gather(const bf16* full, const int* ids, void* out, const int* flags) {
    int idx = blockIdx.x * 256 + threadIdx.x;
    if (idx >= 64 * DD) return;
    int t = idx / DD, d = idx - t * DD;
    float v = __bfloat162float(full[(size_t)ids[t] * DD + d]);
    if (flags[0]) ((float*)out)[idx] = v;
    else ((bf16*)out)[idx] = __float2bfloat16(v);
}

extern "C" void kernel_launch(void* const* d_in, const int* in_sizes, int n_in,
                              void* d_out, int out_size, void* d_ws, size_t ws_size,
                              hipStream_t stream) {
    const void* emb = d_in[0];
    const void* Whd = d_in[1];
    const void* ahd = d_in[2];
    const void* wth = d_in[3];
    const void* Wo  = d_in[4];
    const void* ao  = d_in[5];
    const void* wto = d_in[6];
    const void* adj = d_in[7];
    const int* tid  = (const int*)d_in[8];

    char* p = (char*)d_ws;
    auto alloc = [&](size_t bytes) { void* r = (void*)p; p += ((bytes + 255) / 256) * 256; return r; };
    int*     flags   = (int*)    alloc(256);
    uint8_t* adjbits = (uint8_t*)alloc((size_t)NND * NB8);
    bf16*  X1t   = (bf16*) alloc((size_t)APAD * NND * 2);    // emb^T, padded to 320 rows
    bf16*  x2    = (bf16*) alloc((size_t)NND * F2 * 2);
    bf16*  cc4   = (bf16*) alloc((size_t)HH * NND * 2 * DD * 2);
    bf16*  wtT4  = (bf16*) alloc((size_t)HH * DD * 2 * DD * 2);   // wth^T per head [300][600]
    bf16*  wtTo  = (bf16*) alloc((size_t)DD * 2 * F2 * 2);        // wto^T [300][2400]
    bf16*  Zbuf  = (bf16*) alloc((size_t)2 * AS * 2);        // [sign][320][3072]
    bf16*  ofull = (bf16*) alloc((size_t)NND * DD * 2);
    float* uh1   = (float*)alloc((size_t)HH * DD * 4);
    float* uh2   = (float*)alloc((size_t)HH * DD * 4);
    float* uo1   = (float*)alloc((size_t)F2 * 4);
    float* uo2   = (float*)alloc((size_t)F2 * 4);
    float* Wh1h  = (float*)alloc((size_t)HH * NND * 4);
    float* Wh2h  = (float*)alloc((size_t)HH * NND * 4);
    float* Wh1o  = (float*)alloc((size_t)NND * 4);
    float* Wh2o  = (float*)alloc((size_t)NND * 4);

    dim3 tb(32, 8);
    k_detect<<<1, 64, 0, stream>>>(emb, adj, flags);
    k_adjpack<<<NND, NB8, 0, stream>>>(adj, flags, adjbits);
    hipMemsetAsync(X1t, 0, (size_t)APAD * NND * 2, stream);
    hipMemsetAsync(Zbuf, 0, (size_t)2 * AS * 2, stream);
    // X1t = emb^T: [3072][300] -> [300pad320][3072], grid (10, 96)
    k_transpose<<<dim3((DD + 31) / 32, (NND + 31) / 32), tb, 0, stream>>>(emb, 0, X1t, NND, DD, flags, 1);
    k_uvec<<<dim3((DD + 3) / 4, HH), 256, 0, stream>>>(Whd, ahd, uh1, uh2, DD, DD,
                                                       (long)DD * DD, (long)2 * DD, DD, flags);
    k_gemv2<<<dim3(NND / 4, HH), 256, 0, stream>>>(emb, uh1, uh2, Wh1h, Wh2h, NND, DD, DD, NND, flags, 1);
    // heads fused attention (fat IBLK=48, R22-proven): grid (64, 4, 4) -> cc4
    k_fatt2<<<dim3(64, 4, HH), 256, 0, stream>>>(Wh1h, Wh2h, NND, adjbits, X1t, cc4,
                                                 (long)NND * 2 * DD, 2 * DD, DD);
    // wth^T per head: [600][300] -> [300][600], grid (10, 19)
    for (int l = 0; l < HH; l++)
        k_transpose<<<dim3((DD + 31) / 32, (2 * DD + 31) / 32), tb, 0, stream>>>(
            wth, (size_t)l * 2 * DD * DD, wtT4 + (size_t)l * DD * 2 * DD, 2 * DD, DD, flags, 1);
    // heads concat GEMM + ELU -> x2 column blocks: grid (5, 96, 4)
    k_ccgemm<<<dim3(5, 96, HH), 256, 0, stream>>>(cc4, wtT4, x2, 2 * DD, DD, F2, 0, 0,
                                                  (long)NND * 2 * DD, (long)DD * 2 * DD, DD);
    // output layer (re-associated): wto^T, Z = (x2 @ wto_{p,n})^T
    k_transpose<<<dim3((DD + 31) / 32, (2 * F2 + 31) / 32), tb, 0, stream>>>(
        wto, 0, wtTo, 2 * F2, DD, flags, 1);
    k_ygemm<<<dim3(48, 10, 2), 256, 0, stream>>>(wtTo, 0, F2, 2 * F2, x2, F2, Zbuf);
    k_uvec<<<dim3((F2 + 3) / 4, 1), 256, 0, stream>>>(Wo, ao, uo1, uo2, F2, DD, 0, 0, 0, flags);
    k_gemv2<<<dim3(NND / 4, 1), 256, 0, stream>>>(x2, uo1, uo2, Wh1o, Wh2o, NND, F2, 0, 0, flags, 0);
    // output fused attention+projection (fat IBLK=48) -> ofull (sigmoid): grid (64, 4, 1)
    k_fatt7<<<dim3(64, 4, 1), 256, 0, stream>>>(Wh1o, Wh2o, 0, adjbits, Zbuf,
                                                ofull, DD, 0, 1);
    k_gather<<<(64 * DD + 255) / 256, 256, 0, stream>>>(ofull, tid, d_out, flags);
}

// Round 24
// 316.367 us; speedup vs baseline: 1.1771x; 1.1771x over previous
//
#include <hip/hip_runtime.h>
#include <hip/hip_bf16.h>
#include <stdint.h>

#define NND 3072
#define NB8 (NND / 8)      // adjbits row bytes = 384
#define DD 300
#define HH 4
#define F2 1200
#define TNC 40             // ccgemm/ygemm LDS pad (32 + 8)
#define MREP 5             // fatt feature sub-tiles per wave (80 features)
#define PANEL (MREP * 16)
#define KQ (NND / 4)       // per-wave K-quarter (768)
#define APAD 320           // padded feature rows of Z buffers
#define AS ((size_t)APAD * NND)   // elements per Z slot

typedef __attribute__((ext_vector_type(8))) short short8v;
typedef __attribute__((ext_vector_type(4))) float f32x4;
typedef __hip_bfloat16 bf16;

__device__ inline float ldin(const void* p, size_t i, int isf32) {
    return isf32 ? ((const float*)p)[i]
                 : __bfloat162float(((const bf16*)p)[i]);
}

__device__ inline ushort f2bf(float x) {
    bf16 t = __float2bfloat16(x);
    return *reinterpret_cast<ushort*>(&t);
}

__device__ inline uint pack2(float lo, float hi) {
    return (uint)f2bf(lo) | ((uint)f2bf(hi) << 16);
}

// ---- dtype sniffer: flags[0]=1 iff float inputs are f32; flags[1]=1 iff adj is int32
__global__ void k_detect(const void* emb, const void* adj, int* flags) {
    if (threadIdx.x == 0 && blockIdx.x == 0) {
        const uint16_t* u = (const uint16_t*)emb;
        int plaus = 0;
        for (int i = 0; i < 128; i++) {
            int e = (u[i] >> 7) & 0xFF;
            if (e >= 112 && e <= 143) plaus++;
        }
        flags[0] = (plaus < 100) ? 1 : 0;
        const uint8_t* b = (const uint8_t*)adj;
        int nz = 0;
        for (int i = 0; i < 256; i++) if ((i & 3) != 0 && b[i]) nz++;
        flags[1] = (nz == 0) ? 1 : 0;
    }
}

// ---- pack adjacency to 1 bit per entry: adjbits[i][j/8]
__global__ void k_adjpack(const void* adj, const int* flags, uint8_t* bits) {
    int i = blockIdx.x, o = threadIdx.x;
    int adjInt = flags[1];
    uint8_t b = 0;
    if (!adjInt) {
        const uint8_t* row = (const uint8_t*)adj + (size_t)i * NND + o * 8;
        uint2 v = *(const uint2*)row;
        #pragma unroll
        for (int jj = 0; jj < 4; jj++) {
            if ((v.x >> (8 * jj)) & 0xffu) b |= 1u << jj;
            if ((v.y >> (8 * jj)) & 0xffu) b |= 1u << (4 + jj);
        }
    } else {
        const int* row = (const int*)adj + (size_t)i * NND + o * 8;
        int4 u = *(const int4*)row;
        int4 v = *(const int4*)(row + 4);
        if (u.x) b |= 1;  if (u.y) b |= 2;   if (u.z) b |= 4;   if (u.w) b |= 8;
        if (v.x) b |= 16; if (v.y) b |= 32;  if (v.z) b |= 64;  if (v.w) b |= 128;
    }
    bits[(size_t)i * NB8 + o] = b;
}

// ---- T[c][r] = A[r][c], output bf16.  grid = ((C+31)/32, (R+31)/32)
__global__ void k_transpose(const void* A, size_t baseOff, bf16* T, int R, int C,
                            const int* flags, int useFlag) {
    __shared__ bf16 t[32][33];
    int isf = useFlag ? flags[0] : 0;
    int rt = blockIdx.y * 32, ct = blockIdx.x * 32;
    int tx = threadIdx.x, ty = threadIdx.y;
    for (int i = 0; i < 4; i++) {
        int r = rt + ty + 8 * i, c = ct + tx;
        if (r < R && c < C)
            t[ty + 8 * i][tx] = __float2bfloat16(ldin(A, baseOff + (size_t)r * C + c, isf));
    }
    __syncthreads();
    for (int i = 0; i < 4; i++) {
        int c = ct + ty + 8 * i, r = rt + tx;
        if (c < C && r < R) T[(size_t)c * R + r] = t[tx][ty + 8 * i];
    }
}

// ---- u1 = W @ a[:C], u2 = W @ a[C:2C]
__global__ void k_uvec(const void* W, const void* a, float* u1, float* u2, int R, int C,
                       long Wb, long ab, long ub, const int* flags) {
    int isf = flags[0];
    int h = blockIdx.y;
    int wid = threadIdx.x >> 6, lane = threadIdx.x & 63;
    int r = blockIdx.x * 4 + wid;
    if (r >= R) return;
    float s1 = 0.f, s2 = 0.f;
    for (int c = lane; c < C; c += 64) {
        float w = ldin(W, (size_t)h * Wb + (size_t)r * C + c, isf);
        s1 += w * ldin(a, (size_t)h * ab + c, isf);
        s2 += w * ldin(a, (size_t)h * ab + C + c, isf);
    }
    for (int o = 32; o; o >>= 1) { s1 += __shfl_down(s1, o); s2 += __shfl_down(s2, o); }
    if (lane == 0) { u1[(size_t)h * ub + r] = s1; u2[(size_t)h * ub + r] = s2; }
}

// ---- o1[i] = X[i,:]·u1, o2[i] = X[i,:]·u2
__global__ void k_gemv2(const void* X, const float* u1, const float* u2, float* o1, float* o2,
                        int M, int K, long ub, long ob, const int* flags, int useFlag) {
    int isf = useFlag ? flags[0] : 0;
    int h = blockIdx.y;
    const float* U1 = u1 + (size_t)h * ub;
    const float* U2 = u2 + (size_t)h * ub;
    int wid = threadIdx.x >> 6, lane = threadIdx.x & 63;
    int row = blockIdx.x * 4 + wid;
    if (row >= M) return;
    float s1 = 0.f, s2 = 0.f;
    for (int k = lane; k < K; k += 64) {
        float x = ldin(X, (size_t)row * K + k, isf);
        s1 += x * U1[k]; s2 += x * U2[k];
    }
    for (int o = 32; o; o >>= 1) { s1 += __shfl_down(s1, o); s2 += __shfl_down(s2, o); }
    if (lane == 0) { o1[(size_t)h * ob + row] = s1; o2[(size_t)h * ob + row] = s2; }
}

// ---- fused attention GEMM, fat i-tile (IBLK=48, R22-proven byte-identical):
// 5 A-loads feed 30 MFMAs per k-step. acc[5][3][2]=120 AGPR. __expf fast path.
__global__ __launch_bounds__(256, 2) void k_fatt2(
    const float* __restrict__ Wh1A, const float* __restrict__ Wh2A, long hs,
    const uint8_t* __restrict__ adjbits,
    const bf16* __restrict__ Xt,           // [rowsPad][NND] feature-major, zero-padded
    bf16* __restrict__ CC, long ccHeadStride, int ccStride, int F) {
    __shared__ float lmerge[126][64];      // 120 acc + 6 sums, idx-major (conflict-free)
    int h = blockIdx.z;
    const float* Wh1 = Wh1A + (size_t)h * hs;
    const float* Wh2 = Wh2A + (size_t)h * hs;
    bf16* C = CC + (size_t)h * ccHeadStride;
    int w = threadIdx.x >> 6, lane = threadIdx.x & 63;
    int fbase = blockIdx.y * PANEL;
    int ibase = blockIdx.x * 48;
    int li = lane & 15;
    int ksh = (lane >> 4) * 8;             // k-octet offset within 32-k step
    float w1v[3];
    const uint8_t* abv[3];
    #pragma unroll
    for (int t = 0; t < 3; t++) {
        w1v[t] = Wh1[ibase + t * 16 + li];
        abv[t] = adjbits + (size_t)(ibase + t * 16 + li) * NB8;
    }
    const bf16* Abase = Xt + (size_t)(fbase + li) * NND + ksh;
    f32x4 acc[MREP][3][2] = {};            // [m][itile][side]
    float sp[3] = {0.f, 0.f, 0.f}, sn[3] = {0.f, 0.f, 0.f};

    int kbeg = w * KQ;
    for (int k0 = kbeg; k0 < kbeg + KQ; k0 += 32) {
        float4 wa = *(const float4*)(Wh2 + k0 + ksh);
        float4 wb = *(const float4*)(Wh2 + k0 + ksh + 4);
        float zs0 = wa.x, zs1 = wa.y, zs2 = wa.z, zs3 = wa.w;
        float zs4 = wb.x, zs5 = wb.y, zs6 = wb.z, zs7 = wb.w;
        short8v bp[3], bq[3];
        #pragma unroll
        for (int t = 0; t < 3; t++) {
            uint m1 = *(const uint*)(abv[t] + (k0 >> 3));
            #pragma unroll
            for (int jj = 0; jj < 8; jj++) {
                float zj = (jj == 0) ? zs0 : (jj == 1) ? zs1 : (jj == 2) ? zs2 : (jj == 3) ? zs3
                         : (jj == 4) ? zs4 : (jj == 5) ? zs5 : (jj == 6) ? zs6 : zs7;
                bool on = (m1 >> (ksh + jj)) & 1u;
                float z1 = w1v[t] + zj;
                float e1 = fmaxf(z1, 0.3f * z1);   // leaky_relu(0.3)
                float pe = on ? __expf(e1) : 0.0f;
                float qe = on ? __expf(-e1) : 0.0f;
                sp[t] += pe; sn[t] += qe;
                bp[t][jj] = (short)f2bf(pe); bq[t][jj] = (short)f2bf(qe);
            }
        }
        #pragma unroll
        for (int m = 0; m < MREP; m++) {
            short8v a = *(const short8v*)(Abase + (size_t)m * 16 * NND + k0);
            #pragma unroll
            for (int t = 0; t < 3; t++) {
                acc[m][t][0] = __builtin_amdgcn_mfma_f32_16x16x32_bf16(a, bp[t], acc[m][t][0], 0, 0, 0);
                acc[m][t][1] = __builtin_amdgcn_mfma_f32_16x16x32_bf16(a, bq[t], acc[m][t][1], 0, 0, 0);
            }
        }
    }

    // ---- K-quarter merge: waves 1..3 deposit in turn; wave0 accumulates.
    #pragma unroll
    for (int tt = 1; tt < 4; tt++) {
        if (w == tt) {
            #pragma unroll
            for (int m = 0; m < MREP; m++)
                #pragma unroll
                for (int t = 0; t < 3; t++)
                    #pragma unroll
                    for (int s = 0; s < 2; s++)
                        #pragma unroll
                        for (int r = 0; r < 4; r++)
                            lmerge[((m * 3 + t) * 2 + s) * 4 + r][lane] = acc[m][t][s][r];
            #pragma unroll
            for (int t = 0; t < 3; t++) {
                lmerge[120 + t][lane] = sp[t];
                lmerge[123 + t][lane] = sn[t];
            }
        }
        __syncthreads();
        if (w == 0) {
            #pragma unroll
            for (int m = 0; m < MREP; m++)
                #pragma unroll
                for (int t = 0; t < 3; t++)
                    #pragma unroll
                    for (int s = 0; s < 2; s++)
                        #pragma unroll
                        for (int r = 0; r < 4; r++)
                            acc[m][t][s][r] += lmerge[((m * 3 + t) * 2 + s) * 4 + r][lane];
            #pragma unroll
            for (int t = 0; t < 3; t++) {
                sp[t] += lmerge[120 + t][lane];
                sn[t] += lmerge[123 + t][lane];
            }
        }
        __syncthreads();
    }
    if (w != 0) return;

    #pragma unroll
    for (int t = 0; t < 3; t++) {
        sp[t] += __shfl_xor(sp[t], 16); sp[t] += __shfl_xor(sp[t], 32);
        sn[t] += __shfl_xor(sn[t], 16); sn[t] += __shfl_xor(sn[t], 32);
    }
    int fo = (lane >> 4) * 4;
    #pragma unroll
    for (int t = 0; t < 3; t++) {
        float sc[2] = { 1.0f / sp[t], -1.0f / sn[t] };
        bf16* crow = C + (size_t)(ibase + t * 16 + li) * ccStride;
        #pragma unroll
        for (int m = 0; m < MREP; m++) {
            int fc = fbase + m * 16 + fo;
            if (fc >= F) continue;
            #pragma unroll
            for (int side = 0; side < 2; side++) {
                uint2 uv;
                uv.x = pack2(acc[m][t][side][0] * sc[side], acc[m][t][side][1] * sc[side]);
                uv.y = pack2(acc[m][t][side][2] * sc[side], acc[m][t][side][3] * sc[side]);
                *(uint2*)(crow + side * F + fc) = uv;
            }
        }
    }
}

// ---- Out[:,off:off+N] = epi(A @ Bt^T); M-tile 32, N-tile 64; head-batched via blockIdx.z
__global__ __launch_bounds__(256) void k_ccgemm(const bf16* __restrict__ A0, const bf16* __restrict__ Bt0,
                                                bf16* __restrict__ Out, int K, int Ncols,
                                                int outStride, int outColOff0, int mode,
                                                long aHeadStride, long btHeadStride, int outColStep) {
    __shared__ __align__(16) bf16 Alds[32 * TNC];
    __shared__ __align__(16) bf16 Blds[64 * TNC];
    int h = blockIdx.z;
    const bf16* A = A0 + (size_t)h * aHeadStride;
    const bf16* Bt = Bt0 + (size_t)h * btHeadStride;
    int outColOff = outColOff0 + h * outColStep;
    int tid = threadIdx.x, lane = tid & 63, w = tid >> 6, wr = w >> 1, wc = w & 1;
    int m0 = blockIdx.y * 32, n0 = blockIdx.x * 64;
    int smA = tid >> 3, skA = (tid & 7) * 4;
    int smB = tid >> 2, skB = (tid & 3) * 8;
    f32x4 acc[2] = {};
    for (int k0 = 0; k0 < K; k0 += 32) {
        uint2 va = make_uint2(0, 0);
        uint4 vx = make_uint4(0, 0, 0, 0);
        if (k0 + skA < K) va = *(const uint2*)(A + (size_t)(m0 + smA) * K + k0 + skA);
        if (n0 + smB < Ncols && k0 + skB < K) vx = *(const uint4*)(Bt + (size_t)(n0 + smB) * K + k0 + skB);
        __syncthreads();
        *(uint2*)&Alds[smA * TNC + skA] = va;
        *(uint4*)&Blds[smB * TNC + skB] = vx;
        __syncthreads();
        int arr = wr * 16 + (lane & 15), koff = (lane >> 4) * 8;
        int br = wc * 32 + (lane & 15);
        short8v a0 = *(const short8v*)&Alds[arr * TNC + koff];
        short8v b0 = *(const short8v*)&Blds[br * TNC + koff];
        short8v b1 = *(const short8v*)&Blds[(br + 16) * TNC + koff];
        acc[0] = __builtin_amdgcn_mfma_f32_16x16x32_bf16(a0, b0, acc[0], 0, 0, 0);
        acc[1] = __builtin_amdgcn_mfma_f32_16x16x32_bf16(a0, b1, acc[1], 0, 0, 0);
    }
    for (int ni = 0; ni < 2; ni++) {
        int col = n0 + wc * 32 + ni * 16 + (lane & 15);
        if (col >= Ncols) continue;
        int rbase = m0 + wr * 16 + (lane >> 4) * 4;
        for (int r = 0; r < 4; r++) {
            float v = acc[ni][r];
            if (mode == 0) v = v > 0.f ? v : (__expf(v) - 1.0f);
            else           v = 1.0f / (1.0f + __expf(-v));
            Out[(size_t)(rbase + r) * outStride + outColOff + col] = __float2bfloat16(v);
        }
    }
}

// ---- Zt builder: Out[z][f][i] = sum_k Wt[f][z*coffStep + k] * Bt[i][k]
__global__ __launch_bounds__(256) void k_ygemm(
    const bf16* __restrict__ A0, long aHeadStride, int coffStep, int lda,
    const bf16* __restrict__ Bt, int K,
    bf16* __restrict__ Out0) {
    __shared__ __align__(16) bf16 Alds[32 * TNC];
    __shared__ __align__(16) bf16 Blds[64 * TNC];
    int z = blockIdx.z;
    const bf16* A = A0 + (size_t)(z >> 1) * aHeadStride;
    int coff = (z & 1) * coffStep;
    bf16* Out = Out0 + (size_t)z * AS;
    int tid = threadIdx.x, lane = tid & 63, w = tid >> 6, wr = w >> 1, wc = w & 1;
    int m0 = blockIdx.y * 32, n0 = blockIdx.x * 64;
    int smA = tid >> 3, skA = (tid & 7) * 4;
    int smB = tid >> 2, skB = (tid & 3) * 8;
    f32x4 acc[2] = {};
    for (int k0 = 0; k0 < K; k0 += 32) {
        uint2 va = make_uint2(0, 0);
        uint4 vx = make_uint4(0, 0, 0, 0);
        if (m0 + smA < DD && k0 + skA < K)
            va = *(const uint2*)(A + (size_t)(m0 + smA) * lda + coff + k0 + skA);
        if (k0 + skB < K)
            vx = *(const uint4*)(Bt + (size_t)(n0 + smB) * K + k0 + skB);
        __syncthreads();
        *(uint2*)&Alds[smA * TNC + skA] = va;
        *(uint4*)&Blds[smB * TNC + skB] = vx;
        __syncthreads();
        int arr = wr * 16 + (lane & 15), koff = (lane >> 4) * 8;
        int br = wc * 32 + (lane & 15);
        short8v a0 = *(const short8v*)&Alds[arr * TNC + koff];
        short8v b0 = *(const short8v*)&Blds[br * TNC + koff];
        short8v b1 = *(const short8v*)&Blds[(br + 16) * TNC + koff];
        acc[0] = __builtin_amdgcn_mfma_f32_16x16x32_bf16(a0, b0, acc[0], 0, 0, 0);
        acc[1] = __builtin_amdgcn_mfma_f32_16x16x32_bf16(a0, b1, acc[1], 0, 0, 0);
    }
    for (int ni = 0; ni < 2; ni++) {
        int col = n0 + wc * 32 + ni * 16 + (lane & 15);
        int rbase = m0 + wr * 16 + (lane >> 4) * 4;
        for (int r = 0; r < 4; r++) {
            if (rbase + r < DD)
                Out[(size_t)(rbase + r) * NND + col] = __float2bfloat16(acc[ni][r]);
        }
    }
}

// ---- fused signed attention + projection, fat i-tile (IBLK=48): dual-A,
// 10 A-loads feed 30 MFMAs per k-step (ratio 3, was 2). acc[5][3][2]=120 AGPR.
// __expf fast path (R23's exp2f regression reverted).
__global__ __launch_bounds__(256, 2) void k_fatt7(
    const float* __restrict__ Wh1A, const float* __restrict__ Wh2A, long hs,
    const uint8_t* __restrict__ adjbits,
    const bf16* __restrict__ Aall,
    bf16* __restrict__ Out, int ostride, int ocolStep, int mode) {
    __shared__ float lmerge[126][64];
    int slot = blockIdx.z;
    const float* Wh1 = Wh1A + (size_t)slot * hs;
    const float* Wh2 = Wh2A + (size_t)slot * hs;
    const bf16* Ap = Aall + (size_t)slot * 2 * AS;
    const bf16* An = Ap + AS;
    int ocol = slot * ocolStep;
    int w = threadIdx.x >> 6, lane = threadIdx.x & 63;
    int fbase = blockIdx.y * PANEL;
    int ibase = blockIdx.x * 48;
    int li = lane & 15;
    int ksh = (lane >> 4) * 8;
    float w1v[3];
    const uint8_t* abv[3];
    #pragma unroll
    for (int t = 0; t < 3; t++) {
        w1v[t] = Wh1[ibase + t * 16 + li];
        abv[t] = adjbits + (size_t)(ibase + t * 16 + li) * NB8;
    }
    size_t aoff = (size_t)(fbase + li) * NND + ksh;
    const bf16* Abp = Ap + aoff;
    const bf16* Abn = An + aoff;
    f32x4 acc[MREP][3][2] = {};            // [m][itile][chain p/n]
    float sp[3] = {0.f, 0.f, 0.f}, sn[3] = {0.f, 0.f, 0.f};

    int kbeg = w * KQ;
    for (int k0 = kbeg; k0 < kbeg + KQ; k0 += 32) {
        float4 wa = *(const float4*)(Wh2 + k0 + ksh);
        float4 wb = *(const float4*)(Wh2 + k0 + ksh + 4);
        float zs0 = wa.x, zs1 = wa.y, zs2 = wa.z, zs3 = wa.w;
        float zs4 = wb.x, zs5 = wb.y, zs6 = wb.z, zs7 = wb.w;
        short8v bp[3], bq[3];
        #pragma unroll
        for (int t = 0; t < 3; t++) {
            uint m1 = *(const uint*)(abv[t] + (k0 >> 3));
            #pragma unroll
            for (int jj = 0; jj < 8; jj++) {
                float zj = (jj == 0) ? zs0 : (jj == 1) ? zs1 : (jj == 2) ? zs2 : (jj == 3) ? zs3
                         : (jj == 4) ? zs4 : (jj == 5) ? zs5 : (jj == 6) ? zs6 : zs7;
                bool on = (m1 >> (ksh + jj)) & 1u;
                float z1 = w1v[t] + zj;
                float e1 = fmaxf(z1, 0.3f * z1);
                float pe = on ? __expf(e1) : 0.0f;
                float qe = on ? __expf(-e1) : 0.0f;
                sp[t] += pe; sn[t] += qe;
                bp[t][jj] = (short)f2bf(pe); bq[t][jj] = (short)f2bf(qe);
            }
        }
        #pragma unroll
        for (int m = 0; m < MREP; m++) {
            short8v ap = *(const short8v*)(Abp + (size_t)m * 16 * NND + k0);
            short8v an = *(const short8v*)(Abn + (size_t)m * 16 * NND + k0);
            #pragma unroll
            for (int t = 0; t < 3; t++) {
                acc[m][t][0] = __builtin_amdgcn_mfma_f32_16x16x32_bf16(ap, bp[t], acc[m][t][0], 0, 0, 0);
                acc[m][t][1] = __builtin_amdgcn_mfma_f32_16x16x32_bf16(an, bq[t], acc[m][t][1], 0, 0, 0);
            }
        }
    }

    #pragma unroll
    for (int tt = 1; tt < 4; tt++) {
        if (w == tt) {
            #pragma unroll
            for (int m = 0; m < MREP; m++)
                #pragma unroll
                for (int t = 0; t < 3; t++)
                    #pragma unroll
                    for (int s = 0; s < 2; s++)
                        #pragma unroll
                        for (int r = 0; r < 4; r++)
                            lmerge[((m * 3 + t) * 2 + s) * 4 + r][lane] = acc[m][t][s][r];
            #pragma unroll
            for (int t = 0; t < 3; t++) {
                lmerge[120 + t][lane] = sp[t];
                lmerge[123 + t][lane] = sn[t];
            }
        }
        __syncthreads();
        if (w == 0) {
            #pragma unroll
            for (int m = 0; m < MREP; m++)
                #pragma unroll
                for (int t = 0; t < 3; t++)
                    #pragma unroll
                    for (int s = 0; s < 2; s++)
                        #pragma unroll
                        for (int r = 0; r < 4; r++)
                            acc[m][t][s][r] += lmerge[((m * 3 + t) * 2 + s) * 4 + r][lane];
            #pragma unroll
            for (int t = 0; t < 3; t++) {
                sp[t] += lmerge[120 + t][lane];
                sn[t] += lmerge[123 + t][lane];
            }
        }
        __syncthreads();
    }
    if (w != 0) return;

    #pragma unroll
    for (int t = 0; t < 3; t++) {
        sp[t] += __shfl_xor(sp[t], 16); sp[t] += __shfl_xor(sp[t], 32);
        sn[t] += __shfl_xor(sn[t], 16); sn[t] += __shfl_xor(sn[t], 32);
    }
    int fo = (lane >> 4) * 4;
    #pragma unroll
    for (int t = 0; t < 3; t++) {
        float rp = 1.0f / sp[t], rn = -1.0f / sn[t];
        bf16* crow = Out + (size_t)(ibase + t * 16 + li) * ostride + ocol;
        #pragma unroll
        for (int m = 0; m < MREP; m++) {
            int fc = fbase + m * 16 + fo;
            if (fc >= DD) continue;
            float v1[4];
            #pragma unroll
            for (int r = 0; r < 4; r++) {
                float a = acc[m][t][0][r] * rp + acc[m][t][1][r] * rn;
                if (mode == 0) a = a > 0.f ? a : (__expf(a) - 1.0f);
                else           a = 1.0f / (1.0f + __expf(-a));
                v1[r] = a;
            }
            uint2 uv;
            uv.x = pack2(v1[0], v1[1]); uv.y = pack2(v1[2], v1[3]);
            *(uint2*)(crow + fc) = uv;
        }
    }
}

__global__ void k_gather(const bf16* full, const int* ids, void* out, const int* flags) {
    int idx = blockIdx.x * 256 + threadIdx.x;
    if (idx >= 64 * DD) return;
    int t = idx / DD, d = idx - t * DD;
    float v = __bfloat162float(full[(size_t)ids[t] * DD + d]);
    if (flags[0]) ((float*)out)[idx] = v;
    else ((bf16*)out)[idx] = __float2bfloat16(v);
}

extern "C" void kernel_launch(void* const* d_in, const int* in_sizes, int n_in,
                              void* d_out, int out_size, void* d_ws, size_t ws_size,
                              hipStream_t stream) {
    const void* emb = d_in[0];
    const void* Whd = d_in[1];
    const void* ahd = d_in[2];
    const void* wth = d_in[3];
    const void* Wo  = d_in[4];
    const void* ao  = d_in[5];
    const void* wto = d_in[6];
    const void* adj = d_in[7];
    const int* tid  = (const int*)d_in[8];

    char* p = (char*)d_ws;
    auto alloc = [&](size_t bytes) { void* r = (void*)p; p += ((bytes + 255) / 256) * 256; return r; };
    int*     flags   = (int*)    alloc(256);
    uint8_t* adjbits = (uint8_t*)alloc((size_t)NND * NB8);
    bf16*  X1t   = (bf16*) alloc((size_t)APAD * NND * 2);    // emb^T, padded to 320 rows
    bf16*  x2    = (bf16*) alloc((size_t)NND * F2 * 2);
    bf16*  cc4   = (bf16*) alloc((size_t)HH * NND * 2 * DD * 2);
    bf16*  wtT4  = (bf16*) alloc((size_t)HH * DD * 2 * DD * 2);   // wth^T per head [300][600]
    bf16*  wtTo  = (bf16*) alloc((size_t)DD * 2 * F2 * 2);        // wto^T [300][2400]
    bf16*  Zbuf  = (bf16*) alloc((size_t)2 * AS * 2);        // [sign][320][3072]
    bf16*  ofull = (bf16*) alloc((size_t)NND * DD * 2);
    float* uh1   = (float*)alloc((size_t)HH * DD * 4);
    float* uh2   = (float*)alloc((size_t)HH * DD * 4);
    float* uo1   = (float*)alloc((size_t)F2 * 4);
    float* uo2   = (float*)alloc((size_t)F2 * 4);
    float* Wh1h  = (float*)alloc((size_t)HH * NND * 4);
    float* Wh2h  = (float*)alloc((size_t)HH * NND * 4);
    float* Wh1o  = (float*)alloc((size_t)NND * 4);
    float* Wh2o  = (float*)alloc((size_t)NND * 4);

    dim3 tb(32, 8);
    k_detect<<<1, 64, 0, stream>>>(emb, adj, flags);
    k_adjpack<<<NND, NB8, 0, stream>>>(adj, flags, adjbits);
    hipMemsetAsync(X1t, 0, (size_t)APAD * NND * 2, stream);
    hipMemsetAsync(Zbuf, 0, (size_t)2 * AS * 2, stream);
    // X1t = emb^T: [3072][300] -> [300pad320][3072], grid (10, 96)
    k_transpose<<<dim3((DD + 31) / 32, (NND + 31) / 32), tb, 0, stream>>>(emb, 0, X1t, NND, DD, flags, 1);
    k_uvec<<<dim3((DD + 3) / 4, HH), 256, 0, stream>>>(Whd, ahd, uh1, uh2, DD, DD,
                                                       (long)DD * DD, (long)2 * DD, DD, flags);
    k_gemv2<<<dim3(NND / 4, HH), 256, 0, stream>>>(emb, uh1, uh2, Wh1h, Wh2h, NND, DD, DD, NND, flags, 1);
    // heads fused attention (fat IBLK=48, R22-proven): grid (64, 4, 4) -> cc4
    k_fatt2<<<dim3(64, 4, HH), 256, 0, stream>>>(Wh1h, Wh2h, NND, adjbits, X1t, cc4,
                                                 (long)NND * 2 * DD, 2 * DD, DD);
    // wth^T per head: [600][300] -> [300][600], grid (10, 19)
    for (int l = 0; l < HH; l++)
        k_transpose<<<dim3((DD + 31) / 32, (2 * DD + 31) / 32), tb, 0, stream>>>(
            wth, (size_t)l * 2 * DD * DD, wtT4 + (size_t)l * DD * 2 * DD, 2 * DD, DD, flags, 1);
    // heads concat GEMM + ELU -> x2 column blocks: grid (5, 96, 4)
    k_ccgemm<<<dim3(5, 96, HH), 256, 0, stream>>>(cc4, wtT4, x2, 2 * DD, DD, F2, 0, 0,
                                                  (long)NND * 2 * DD, (long)DD * 2 * DD, DD);
    // output layer (re-associated): wto^T, Z = (x2 @ wto_{p,n})^T
    k_transpose<<<dim3((DD + 31) / 32, (2 * F2 + 31) / 32), tb, 0, stream>>>(
        wto, 0, wtTo, 2 * F2, DD, flags, 1);
    k_ygemm<<<dim3(48, 10, 2), 256, 0, stream>>>(wtTo, 0, F2, 2 * F2, x2, F2, Zbuf);
    k_uvec<<<dim3((F2 + 3) / 4, 1), 256, 0, stream>>>(Wo, ao, uo1, uo2, F2, DD, 0, 0, 0, flags);
    k_gemv2<<<dim3(NND / 4, 1), 256, 0, stream>>>(x2, uo1, uo2, Wh1o, Wh2o, NND, F2, 0, 0, flags, 0);
    // output fused attention+projection (fat IBLK=48) -> ofull (sigmoid): grid (64, 4, 1)
    k_fatt7<<<dim3(64, 4, 1), 256, 0, stream>>>(Wh1o, Wh2o, 0, adjbits, Zbuf,
                                                ofull, DD, 0, 1);
    k_gather<<<(64 * DD + 255) / 256, 256, 0, stream>>>(ofull, tid, d_out, flags);
}

// Round 25
// 295.768 us; speedup vs baseline: 1.2591x; 1.0696x over previous
//
#include <hip/hip_runtime.h>
#include <hip/hip_bf16.h>
#include <stdint.h>

#define NND 3072
#define NB8 (NND / 8)      // adjbits row bytes = 384
#define DD 300
#define HH 4
#define F2 1200
#define TNC 40             // ccgemm/ygemm LDS pad (32 + 8)
#define MREP 5             // fatt feature sub-tiles per wave (80 features)
#define PANEL (MREP * 16)
#define KQ (NND / 4)       // per-wave K-quarter (768)
#define APAD 320           // padded feature rows of Z buffers
#define AS ((size_t)APAD * NND)   // elements per Z slot

typedef __attribute__((ext_vector_type(8))) short short8v;
typedef __attribute__((ext_vector_type(4))) float f32x4;
typedef __hip_bfloat16 bf16;

__device__ inline float ldin(const void* p, size_t i, int isf32) {
    return isf32 ? ((const float*)p)[i]
                 : __bfloat162float(((const bf16*)p)[i]);
}

__device__ inline ushort f2bf(float x) {
    bf16 t = __float2bfloat16(x);
    return *reinterpret_cast<ushort*>(&t);
}

__device__ inline uint pack2(float lo, float hi) {
    return (uint)f2bf(lo) | ((uint)f2bf(hi) << 16);
}

// ---- dtype sniffer: flags[0]=1 iff float inputs are f32; flags[1]=1 iff adj is int32
__global__ void k_detect(const void* emb, const void* adj, int* flags) {
    if (threadIdx.x == 0 && blockIdx.x == 0) {
        const uint16_t* u = (const uint16_t*)emb;
        int plaus = 0;
        for (int i = 0; i < 128; i++) {
            int e = (u[i] >> 7) & 0xFF;
            if (e >= 112 && e <= 143) plaus++;
        }
        flags[0] = (plaus < 100) ? 1 : 0;
        const uint8_t* b = (const uint8_t*)adj;
        int nz = 0;
        for (int i = 0; i < 256; i++) if ((i & 3) != 0 && b[i]) nz++;
        flags[1] = (nz == 0) ? 1 : 0;
    }
}

// ---- pack adjacency to 1 bit per entry: adjbits[i][j/8]
__global__ void k_adjpack(const void* adj, const int* flags, uint8_t* bits) {
    int i = blockIdx.x, o = threadIdx.x;
    int adjInt = flags[1];
    uint8_t b = 0;
    if (!adjInt) {
        const uint8_t* row = (const uint8_t*)adj + (size_t)i * NND + o * 8;
        uint2 v = *(const uint2*)row;
        #pragma unroll
        for (int jj = 0; jj < 4; jj++) {
            if ((v.x >> (8 * jj)) & 0xffu) b |= 1u << jj;
            if ((v.y >> (8 * jj)) & 0xffu) b |= 1u << (4 + jj);
        }
    } else {
        const int* row = (const int*)adj + (size_t)i * NND + o * 8;
        int4 u = *(const int4*)row;
        int4 v = *(const int4*)(row + 4);
        if (u.x) b |= 1;  if (u.y) b |= 2;   if (u.z) b |= 4;   if (u.w) b |= 8;
        if (v.x) b |= 16; if (v.y) b |= 32;  if (v.z) b |= 64;  if (v.w) b |= 128;
    }
    bits[(size_t)i * NB8 + o] = b;
}

// ---- T[c][r] = A[r][c], output bf16.  grid = ((C+31)/32, (R+31)/32, nz)
// per-z input offset = z*zInStep, output offset = z*zOutStep
__global__ void k_transpose(const void* A, size_t baseOff, bf16* T, int R, int C,
                            const int* flags, int useFlag, long zInStep, long zOutStep) {
    __shared__ bf16 t[32][33];
    int isf = useFlag ? flags[0] : 0;
    size_t inOff = baseOff + (size_t)blockIdx.z * zInStep;
    bf16* To = T + (size_t)blockIdx.z * zOutStep;
    int rt = blockIdx.y * 32, ct = blockIdx.x * 32;
    int tx = threadIdx.x, ty = threadIdx.y;
    for (int i = 0; i < 4; i++) {
        int r = rt + ty + 8 * i, c = ct + tx;
        if (r < R && c < C)
            t[ty + 8 * i][tx] = __float2bfloat16(ldin(A, inOff + (size_t)r * C + c, isf));
    }
    __syncthreads();
    for (int i = 0; i < 4; i++) {
        int c = ct + ty + 8 * i, r = rt + tx;
        if (c < C && r < R) To[(size_t)c * R + r] = t[tx][ty + 8 * i];
    }
}

// ---- u1 = W @ a[:C], u2 = W @ a[C:2C]
__global__ void k_uvec(const void* W, const void* a, float* u1, float* u2, int R, int C,
                       long Wb, long ab, long ub, const int* flags) {
    int isf = flags[0];
    int h = blockIdx.y;
    int wid = threadIdx.x >> 6, lane = threadIdx.x & 63;
    int r = blockIdx.x * 4 + wid;
    if (r >= R) return;
    float s1 = 0.f, s2 = 0.f;
    for (int c = lane; c < C; c += 64) {
        float w = ldin(W, (size_t)h * Wb + (size_t)r * C + c, isf);
        s1 += w * ldin(a, (size_t)h * ab + c, isf);
        s2 += w * ldin(a, (size_t)h * ab + C + c, isf);
    }
    for (int o = 32; o; o >>= 1) { s1 += __shfl_down(s1, o); s2 += __shfl_down(s2, o); }
    if (lane == 0) { u1[(size_t)h * ub + r] = s1; u2[(size_t)h * ub + r] = s2; }
}

// ---- o1[i] = X[i,:]·u1, o2[i] = X[i,:]·u2
__global__ void k_gemv2(const void* X, const float* u1, const float* u2, float* o1, float* o2,
                        int M, int K, long ub, long ob, const int* flags, int useFlag) {
    int isf = useFlag ? flags[0] : 0;
    int h = blockIdx.y;
    const float* U1 = u1 + (size_t)h * ub;
    const float* U2 = u2 + (size_t)h * ub;
    int wid = threadIdx.x >> 6, lane = threadIdx.x & 63;
    int row = blockIdx.x * 4 + wid;
    if (row >= M) return;
    float s1 = 0.f, s2 = 0.f;
    for (int k = lane; k < K; k += 64) {
        float x = ldin(X, (size_t)row * K + k, isf);
        s1 += x * U1[k]; s2 += x * U2[k];
    }
    for (int o = 32; o; o >>= 1) { s1 += __shfl_down(s1, o); s2 += __shfl_down(s2, o); }
    if (lane == 0) { o1[(size_t)h * ob + row] = s1; o2[(size_t)h * ob + row] = s2; }
}

// ---- fused attention GEMM, fat i-tile (IBLK=48, R22/R24-proven):
// 5 A-loads feed 30 MFMAs per k-step. acc[5][3][2]=120 AGPR. __expf fast path.
__global__ __launch_bounds__(256, 2) void k_fatt2(
    const float* __restrict__ Wh1A, const float* __restrict__ Wh2A, long hs,
    const uint8_t* __restrict__ adjbits,
    const bf16* __restrict__ Xt,           // [rowsPad][NND] feature-major, zero-padded
    bf16* __restrict__ CC, long ccHeadStride, int ccStride, int F) {
    __shared__ float lmerge[126][64];      // 120 acc + 6 sums, idx-major (conflict-free)
    int h = blockIdx.z;
    const float* Wh1 = Wh1A + (size_t)h * hs;
    const float* Wh2 = Wh2A + (size_t)h * hs;
    bf16* C = CC + (size_t)h * ccHeadStride;
    int w = threadIdx.x >> 6, lane = threadIdx.x & 63;
    int fbase = blockIdx.y * PANEL;
    int ibase = blockIdx.x * 48;
    int li = lane & 15;
    int ksh = (lane >> 4) * 8;             // k-octet offset within 32-k step
    float w1v[3];
    const uint8_t* abv[3];
    #pragma unroll
    for (int t = 0; t < 3; t++) {
        w1v[t] = Wh1[ibase + t * 16 + li];
        abv[t] = adjbits + (size_t)(ibase + t * 16 + li) * NB8;
    }
    const bf16* Abase = Xt + (size_t)(fbase + li) * NND + ksh;
    f32x4 acc[MREP][3][2] = {};            // [m][itile][side]
    float sp[3] = {0.f, 0.f, 0.f}, sn[3] = {0.f, 0.f, 0.f};

    int kbeg = w * KQ;
    for (int k0 = kbeg; k0 < kbeg + KQ; k0 += 32) {
        float4 wa = *(const float4*)(Wh2 + k0 + ksh);
        float4 wb = *(const float4*)(Wh2 + k0 + ksh + 4);
        float zs0 = wa.x, zs1 = wa.y, zs2 = wa.z, zs3 = wa.w;
        float zs4 = wb.x, zs5 = wb.y, zs6 = wb.z, zs7 = wb.w;
        short8v bp[3], bq[3];
        #pragma unroll
        for (int t = 0; t < 3; t++) {
            uint m1 = *(const uint*)(abv[t] + (k0 >> 3));
            #pragma unroll
            for (int jj = 0; jj < 8; jj++) {
                float zj = (jj == 0) ? zs0 : (jj == 1) ? zs1 : (jj == 2) ? zs2 : (jj == 3) ? zs3
                         : (jj == 4) ? zs4 : (jj == 5) ? zs5 : (jj == 6) ? zs6 : zs7;
                bool on = (m1 >> (ksh + jj)) & 1u;
                float z1 = w1v[t] + zj;
                float e1 = fmaxf(z1, 0.3f * z1);   // leaky_relu(0.3)
                float pe = on ? __expf(e1) : 0.0f;
                float qe = on ? __expf(-e1) : 0.0f;
                sp[t] += pe; sn[t] += qe;
                bp[t][jj] = (short)f2bf(pe); bq[t][jj] = (short)f2bf(qe);
            }
        }
        #pragma unroll
        for (int m = 0; m < MREP; m++) {
            short8v a = *(const short8v*)(Abase + (size_t)m * 16 * NND + k0);
            #pragma unroll
            for (int t = 0; t < 3; t++) {
                acc[m][t][0] = __builtin_amdgcn_mfma_f32_16x16x32_bf16(a, bp[t], acc[m][t][0], 0, 0, 0);
                acc[m][t][1] = __builtin_amdgcn_mfma_f32_16x16x32_bf16(a, bq[t], acc[m][t][1], 0, 0, 0);
            }
        }
    }

    // ---- K-quarter merge: waves 1..3 deposit in turn; wave0 accumulates.
    #pragma unroll
    for (int tt = 1; tt < 4; tt++) {
        if (w == tt) {
            #pragma unroll
            for (int m = 0; m < MREP; m++)
                #pragma unroll
                for (int t = 0; t < 3; t++)
                    #pragma unroll
                    for (int s = 0; s < 2; s++)
                        #pragma unroll
                        for (int r = 0; r < 4; r++)
                            lmerge[((m * 3 + t) * 2 + s) * 4 + r][lane] = acc[m][t][s][r];
            #pragma unroll
            for (int t = 0; t < 3; t++) {
                lmerge[120 + t][lane] = sp[t];
                lmerge[123 + t][lane] = sn[t];
            }
        }
        __syncthreads();
        if (w == 0) {
            #pragma unroll
            for (int m = 0; m < MREP; m++)
                #pragma unroll
                for (int t = 0; t < 3; t++)
                    #pragma unroll
                    for (int s = 0; s < 2; s++)
                        #pragma unroll
                        for (int r = 0; r < 4; r++)
                            acc[m][t][s][r] += lmerge[((m * 3 + t) * 2 + s) * 4 + r][lane];
            #pragma unroll
            for (int t = 0; t < 3; t++) {
                sp[t] += lmerge[120 + t][lane];
                sn[t] += lmerge[123 + t][lane];
            }
        }
        __syncthreads();
    }
    if (w != 0) return;

    #pragma unroll
    for (int t = 0; t < 3; t++) {
        sp[t] += __shfl_xor(sp[t], 16); sp[t] += __shfl_xor(sp[t], 32);
        sn[t] += __shfl_xor(sn[t], 16); sn[t] += __shfl_xor(sn[t], 32);
    }
    int fo = (lane >> 4) * 4;
    #pragma unroll
    for (int t = 0; t < 3; t++) {
        float sc[2] = { 1.0f / sp[t], -1.0f / sn[t] };
        bf16* crow = C + (size_t)(ibase + t * 16 + li) * ccStride;
        #pragma unroll
        for (int m = 0; m < MREP; m++) {
            int fc = fbase + m * 16 + fo;
            if (fc >= F) continue;
            #pragma unroll
            for (int side = 0; side < 2; side++) {
                uint2 uv;
                uv.x = pack2(acc[m][t][side][0] * sc[side], acc[m][t][side][1] * sc[side]);
                uv.y = pack2(acc[m][t][side][2] * sc[side], acc[m][t][side][3] * sc[side]);
                *(uint2*)(crow + side * F + fc) = uv;
            }
        }
    }
}

// ---- Out[:,off:off+N] = epi(A @ Bt^T); M-tile 32, N-tile 64; head-batched via blockIdx.z
__global__ __launch_bounds__(256) void k_ccgemm(const bf16* __restrict__ A0, const bf16* __restrict__ Bt0,
                                                bf16* __restrict__ Out, int K, int Ncols,
                                                int outStride, int outColOff0, int mode,
                                                long aHeadStride, long btHeadStride, int outColStep) {
    __shared__ __align__(16) bf16 Alds[32 * TNC];
    __shared__ __align__(16) bf16 Blds[64 * TNC];
    int h = blockIdx.z;
    const bf16* A = A0 + (size_t)h * aHeadStride;
    const bf16* Bt = Bt0 + (size_t)h * btHeadStride;
    int outColOff = outColOff0 + h * outColStep;
    int tid = threadIdx.x, lane = tid & 63, w = tid >> 6, wr = w >> 1, wc = w & 1;
    int m0 = blockIdx.y * 32, n0 = blockIdx.x * 64;
    int smA = tid >> 3, skA = (tid & 7) * 4;
    int smB = tid >> 2, skB = (tid & 3) * 8;
    f32x4 acc[2] = {};
    for (int k0 = 0; k0 < K; k0 += 32) {
        uint2 va = make_uint2(0, 0);
        uint4 vx = make_uint4(0, 0, 0, 0);
        if (k0 + skA < K) va = *(const uint2*)(A + (size_t)(m0 + smA) * K + k0 + skA);
        if (n0 + smB < Ncols && k0 + skB < K) vx = *(const uint4*)(Bt + (size_t)(n0 + smB) * K + k0 + skB);
        __syncthreads();
        *(uint2*)&Alds[smA * TNC + skA] = va;
        *(uint4*)&Blds[smB * TNC + skB] = vx;
        __syncthreads();
        int arr = wr * 16 + (lane & 15), koff = (lane >> 4) * 8;
        int br = wc * 32 + (lane & 15);
        short8v a0 = *(const short8v*)&Alds[arr * TNC + koff];
        short8v b0 = *(const short8v*)&Blds[br * TNC + koff];
        short8v b1 = *(const short8v*)&Blds[(br + 16) * TNC + koff];
        acc[0] = __builtin_amdgcn_mfma_f32_16x16x32_bf16(a0, b0, acc[0], 0, 0, 0);
        acc[1] = __builtin_amdgcn_mfma_f32_16x16x32_bf16(a0, b1, acc[1], 0, 0, 0);
    }
    for (int ni = 0; ni < 2; ni++) {
        int col = n0 + wc * 32 + ni * 16 + (lane & 15);
        if (col >= Ncols) continue;
        int rbase = m0 + wr * 16 + (lane >> 4) * 4;
        for (int r = 0; r < 4; r++) {
            float v = acc[ni][r];
            if (mode == 0) v = v > 0.f ? v : (__expf(v) - 1.0f);
            else           v = 1.0f / (1.0f + __expf(-v));
            Out[(size_t)(rbase + r) * outStride + outColOff + col] = __float2bfloat16(v);
        }
    }
}

// ---- Zt builder: Out[z][f][i] = sum_k Wt[f][z*coffStep + k] * Bt[i][k]
__global__ __launch_bounds__(256) void k_ygemm(
    const bf16* __restrict__ A0, long aHeadStride, int coffStep, int lda,
    const bf16* __restrict__ Bt, int K,
    bf16* __restrict__ Out0) {
    __shared__ __align__(16) bf16 Alds[32 * TNC];
    __shared__ __align__(16) bf16 Blds[64 * TNC];
    int z = blockIdx.z;
    const bf16* A = A0 + (size_t)(z >> 1) * aHeadStride;
    int coff = (z & 1) * coffStep;
    bf16* Out = Out0 + (size_t)z * AS;
    int tid = threadIdx.x, lane = tid & 63, w = tid >> 6, wr = w >> 1, wc = w & 1;
    int m0 = blockIdx.y * 32, n0 = blockIdx.x * 64;
    int smA = tid >> 3, skA = (tid & 7) * 4;
    int smB = tid >> 2, skB = (tid & 3) * 8;
    f32x4 acc[2] = {};
    for (int k0 = 0; k0 < K; k0 += 32) {
        uint2 va = make_uint2(0, 0);
        uint4 vx = make_uint4(0, 0, 0, 0);
        if (m0 + smA < DD && k0 + skA < K)
            va = *(const uint2*)(A + (size_t)(m0 + smA) * lda + coff + k0 + skA);
        if (k0 + skB < K)
            vx = *(const uint4*)(Bt + (size_t)(n0 + smB) * K + k0 + skB);
        __syncthreads();
        *(uint2*)&Alds[smA * TNC + skA] = va;
        *(uint4*)&Blds[smB * TNC + skB] = vx;
        __syncthreads();
        int arr = wr * 16 + (lane & 15), koff = (lane >> 4) * 8;
        int br = wc * 32 + (lane & 15);
        short8v a0 = *(const short8v*)&Alds[arr * TNC + koff];
        short8v b0 = *(const short8v*)&Blds[br * TNC + koff];
        short8v b1 = *(const short8v*)&Blds[(br + 16) * TNC + koff];
        acc[0] = __builtin_amdgcn_mfma_f32_16x16x32_bf16(a0, b0, acc[0], 0, 0, 0);
        acc[1] = __builtin_amdgcn_mfma_f32_16x16x32_bf16(a0, b1, acc[1], 0, 0, 0);
    }
    for (int ni = 0; ni < 2; ni++) {
        int col = n0 + wc * 32 + ni * 16 + (lane & 15);
        int rbase = m0 + wr * 16 + (lane >> 4) * 4;
        for (int r = 0; r < 4; r++) {
            if (rbase + r < DD)
                Out[(size_t)(rbase + r) * NND + col] = __float2bfloat16(acc[ni][r]);
        }
    }
}

// ---- fused signed attention + projection (dual-A, IBLK=32, R20/R22-proven):
// Out[i][f] = sigmoid( rsp*sum_j Pp[i][j]*Zp[f][j] + rsn*sum_j Pn[i][j]*Zn[f][j] )
__global__ __launch_bounds__(256, 2) void k_fatt7(
    const float* __restrict__ Wh1A, const float* __restrict__ Wh2A, long hs,
    const uint8_t* __restrict__ adjbits,
    const bf16* __restrict__ Aall,
    bf16* __restrict__ Out, int ostride, int ocolStep, int mode) {
    __shared__ float lmerge[84][64];
    int slot = blockIdx.z;
    const float* Wh1 = Wh1A + (size_t)slot * hs;
    const float* Wh2 = Wh2A + (size_t)slot * hs;
    const bf16* Ap = Aall + (size_t)slot * 2 * AS;
    const bf16* An = Ap + AS;
    int ocol = slot * ocolStep;
    int w = threadIdx.x >> 6, lane = threadIdx.x & 63;
    int fbase = blockIdx.y * PANEL;
    int ibase = blockIdx.x * 32;
    int i1 = ibase + (lane & 15), i2 = i1 + 16;
    int ksh = (lane >> 4) * 8;
    float w1a = Wh1[i1], w1b = Wh1[i2];
    const uint8_t* ab1 = adjbits + (size_t)i1 * NB8;
    const uint8_t* ab2 = adjbits + (size_t)i2 * NB8;
    size_t aoff = (size_t)(fbase + (lane & 15)) * NND + ksh;
    const bf16* Abp = Ap + aoff;
    const bf16* Abn = An + aoff;
    f32x4 acc[MREP][2][2] = {};            // [m][itile][chain p/n]
    float sp1 = 0.f, sn1 = 0.f, sp2 = 0.f, sn2 = 0.f;

    int kbeg = w * KQ;
    for (int k0 = kbeg; k0 < kbeg + KQ; k0 += 32) {
        uint m1 = *(const uint*)(ab1 + (k0 >> 3));
        uint m2 = *(const uint*)(ab2 + (k0 >> 3));
        float4 wa = *(const float4*)(Wh2 + k0 + ksh);
        float4 wb = *(const float4*)(Wh2 + k0 + ksh + 4);
        float zs0 = wa.x, zs1 = wa.y, zs2 = wa.z, zs3 = wa.w;
        float zs4 = wb.x, zs5 = wb.y, zs6 = wb.z, zs7 = wb.w;
        short8v bp1, bq1, bp2, bq2;
        #pragma unroll
        for (int jj = 0; jj < 8; jj++) {
            float zj = (jj == 0) ? zs0 : (jj == 1) ? zs1 : (jj == 2) ? zs2 : (jj == 3) ? zs3
                     : (jj == 4) ? zs4 : (jj == 5) ? zs5 : (jj == 6) ? zs6 : zs7;
            bool on1 = (m1 >> (ksh + jj)) & 1u;
            bool on2 = (m2 >> (ksh + jj)) & 1u;
            float z1 = w1a + zj;
            float e1 = fmaxf(z1, 0.3f * z1);
            float pe1 = on1 ? __expf(e1) : 0.0f;
            float qe1 = on1 ? __expf(-e1) : 0.0f;
            float z2 = w1b + zj;
            float e2 = fmaxf(z2, 0.3f * z2);
            float pe2 = on2 ? __expf(e2) : 0.0f;
            float qe2 = on2 ? __expf(-e2) : 0.0f;
            sp1 += pe1; sn1 += qe1; sp2 += pe2; sn2 += qe2;
            bp1[jj] = (short)f2bf(pe1); bq1[jj] = (short)f2bf(qe1);
            bp2[jj] = (short)f2bf(pe2); bq2[jj] = (short)f2bf(qe2);
        }
        #pragma unroll
        for (int m = 0; m < MREP; m++) {
            short8v ap = *(const short8v*)(Abp + (size_t)m * 16 * NND + k0);
            short8v an = *(const short8v*)(Abn + (size_t)m * 16 * NND + k0);
            acc[m][0][0] = __builtin_amdgcn_mfma_f32_16x16x32_bf16(ap, bp1, acc[m][0][0], 0, 0, 0);
            acc[m][0][1] = __builtin_amdgcn_mfma_f32_16x16x32_bf16(an, bq1, acc[m][0][1], 0, 0, 0);
            acc[m][1][0] = __builtin_amdgcn_mfma_f32_16x16x32_bf16(ap, bp2, acc[m][1][0], 0, 0, 0);
            acc[m][1][1] = __builtin_amdgcn_mfma_f32_16x16x32_bf16(an, bq2, acc[m][1][1], 0, 0, 0);
        }
    }

    #pragma unroll
    for (int t = 1; t < 4; t++) {
        if (w == t) {
            #pragma unroll
            for (int m = 0; m < MREP; m++)
                #pragma unroll
                for (int it = 0; it < 2; it++)
                    #pragma unroll
                    for (int s = 0; s < 2; s++)
                        #pragma unroll
                        for (int r = 0; r < 4; r++)
                            lmerge[((m * 2 + it) * 2 + s) * 4 + r][lane] = acc[m][it][s][r];
            lmerge[80][lane] = sp1; lmerge[81][lane] = sn1;
            lmerge[82][lane] = sp2; lmerge[83][lane] = sn2;
        }
        __syncthreads();
        if (w == 0) {
            #pragma unroll
            for (int m = 0; m < MREP; m++)
                #pragma unroll
                for (int it = 0; it < 2; it++)
                    #pragma unroll
                    for (int s = 0; s < 2; s++)
                        #pragma unroll
                        for (int r = 0; r < 4; r++)
                            acc[m][it][s][r] += lmerge[((m * 2 + it) * 2 + s) * 4 + r][lane];
            sp1 += lmerge[80][lane]; sn1 += lmerge[81][lane];
            sp2 += lmerge[82][lane]; sn2 += lmerge[83][lane];
        }
        __syncthreads();
    }
    if (w != 0) return;

    sp1 += __shfl_xor(sp1, 16); sp1 += __shfl_xor(sp1, 32);
    sn1 += __shfl_xor(sn1, 16); sn1 += __shfl_xor(sn1, 32);
    sp2 += __shfl_xor(sp2, 16); sp2 += __shfl_xor(sp2, 32);
    sn2 += __shfl_xor(sn2, 16); sn2 += __shfl_xor(sn2, 32);
    float rp1 = 1.0f / sp1, rn1 = -1.0f / sn1;
    float rp2 = 1.0f / sp2, rn2 = -1.0f / sn2;
    int fo = (lane >> 4) * 4;
    bf16* crow1 = Out + (size_t)i1 * ostride + ocol;
    bf16* crow2 = Out + (size_t)i2 * ostride + ocol;
    #pragma unroll
    for (int m = 0; m < MREP; m++) {
        int fc = fbase + m * 16 + fo;
        if (fc >= DD) continue;
        float v1[4], v2[4];
        #pragma unroll
        for (int r = 0; r < 4; r++) {
            float a = acc[m][0][0][r] * rp1 + acc[m][0][1][r] * rn1;
            float b = acc[m][1][0][r] * rp2 + acc[m][1][1][r] * rn2;
            if (mode == 0) { a = a > 0.f ? a : (__expf(a) - 1.0f); b = b > 0.f ? b : (__expf(b) - 1.0f); }
            else           { a = 1.0f / (1.0f + __expf(-a));       b = 1.0f / (1.0f + __expf(-b)); }
            v1[r] = a; v2[r] = b;
        }
        uint2 uv;
        uv.x = pack2(v1[0], v1[1]); uv.y = pack2(v1[2], v1[3]);
        *(uint2*)(crow1 + fc) = uv;
        uv.x = pack2(v2[0], v2[1]); uv.y = pack2(v2[2], v2[3]);
        *(uint2*)(crow2 + fc) = uv;
    }
}

__global__ void k_gather(const bf16* full, const int* ids, void* out, const int* flags) {
    int idx = blockIdx.x * 256 + threadIdx.x;
    if (idx >= 64 * DD) return;
    int t = idx / DD, d = idx - t * DD;
    float v = __bfloat162float(full[(size_t)ids[t] * DD + d]);
    if (flags[0]) ((float*)out)[idx] = v;
    else ((bf16*)out)[idx] = __float2bfloat16(v);
}

extern "C" void kernel_launch(void* const* d_in, const int* in_sizes, int n_in,
                              void* d_out, int out_size, void* d_ws, size_t ws_size,
                              hipStream_t stream) {
    const void* emb = d_in[0];
    const void* Whd = d_in[1];
    const void* ahd = d_in[2];
    const void* wth = d_in[3];
    const void* Wo  = d_in[4];
    const void* ao  = d_in[5];
    const void* wto = d_in[6];
    const void* adj = d_in[7];
    const int* tid  = (const int*)d_in[8];

    char* p = (char*)d_ws;
    auto alloc = [&](size_t bytes) { void* r = (void*)p; p += ((bytes + 255) / 256) * 256; return r; };
    int*     flags   = (int*)    alloc(256);
    uint8_t* adjbits = (uint8_t*)alloc((size_t)NND * NB8);
    bf16*  X1t   = (bf16*) alloc((size_t)APAD * NND * 2);    // emb^T, padded to 320 rows
    bf16*  x2    = (bf16*) alloc((size_t)NND * F2 * 2);
    bf16*  cc4   = (bf16*) alloc((size_t)HH * NND * 2 * DD * 2);
    bf16*  wtT4  = (bf16*) alloc((size_t)HH * DD * 2 * DD * 2);   // wth^T per head [300][600]
    bf16*  wtTo  = (bf16*) alloc((size_t)DD * 2 * F2 * 2);        // wto^T [300][2400]
    bf16*  Zbuf  = (bf16*) alloc((size_t)2 * AS * 2);        // [sign][320][3072]
    bf16*  ofull = (bf16*) alloc((size_t)NND * DD * 2);
    float* uh1   = (float*)alloc((size_t)HH * DD * 4);
    float* uh2   = (float*)alloc((size_t)HH * DD * 4);
    float* uo1   = (float*)alloc((size_t)F2 * 4);
    float* uo2   = (float*)alloc((size_t)F2 * 4);
    float* Wh1h  = (float*)alloc((size_t)HH * NND * 4);
    float* Wh2h  = (float*)alloc((size_t)HH * NND * 4);
    float* Wh1o  = (float*)alloc((size_t)NND * 4);
    float* Wh2o  = (float*)alloc((size_t)NND * 4);

    dim3 tb(32, 8);
    k_detect<<<1, 64, 0, stream>>>(emb, adj, flags);
    k_adjpack<<<NND, NB8, 0, stream>>>(adj, flags, adjbits);
    hipMemsetAsync(X1t, 0, (size_t)APAD * NND * 2, stream);
    hipMemsetAsync(Zbuf, 0, (size_t)2 * AS * 2, stream);
    // X1t = emb^T: [3072][300] -> [300pad320][3072], grid (10, 96, 1)
    k_transpose<<<dim3((DD + 31) / 32, (NND + 31) / 32, 1), tb, 0, stream>>>(
        emb, 0, X1t, NND, DD, flags, 1, 0, 0);
    k_uvec<<<dim3((DD + 3) / 4, HH), 256, 0, stream>>>(Whd, ahd, uh1, uh2, DD, DD,
                                                       (long)DD * DD, (long)2 * DD, DD, flags);
    k_gemv2<<<dim3(NND / 4, HH), 256, 0, stream>>>(emb, uh1, uh2, Wh1h, Wh2h, NND, DD, DD, NND, flags, 1);
    // heads fused attention (fat IBLK=48, R22-proven): grid (64, 4, 4) -> cc4
    k_fatt2<<<dim3(64, 4, HH), 256, 0, stream>>>(Wh1h, Wh2h, NND, adjbits, X1t, cc4,
                                                 (long)NND * 2 * DD, 2 * DD, DD);
    // wth^T all heads in one dispatch: [600][300] -> [300][600], grid (10, 19, 4)
    k_transpose<<<dim3((DD + 31) / 32, (2 * DD + 31) / 32, HH), tb, 0, stream>>>(
        wth, 0, wtT4, 2 * DD, DD, flags, 1, (long)2 * DD * DD, (long)DD * 2 * DD);
    // heads concat GEMM + ELU -> x2 column blocks: grid (5, 96, 4)
    k_ccgemm<<<dim3(5, 96, HH), 256, 0, stream>>>(cc4, wtT4, x2, 2 * DD, DD, F2, 0, 0,
                                                  (long)NND * 2 * DD, (long)DD * 2 * DD, DD);
    // output layer (re-associated): wto^T, Z = (x2 @ wto_{p,n})^T
    k_transpose<<<dim3((DD + 31) / 32, (2 * F2 + 31) / 32, 1), tb, 0, stream>>>(
        wto, 0, wtTo, 2 * F2, DD, flags, 1, 0, 0);
    k_ygemm<<<dim3(48, 10, 2), 256, 0, stream>>>(wtTo, 0, F2, 2 * F2, x2, F2, Zbuf);
    k_uvec<<<dim3((F2 + 3) / 4, 1), 256, 0, stream>>>(Wo, ao, uo1, uo2, F2, DD, 0, 0, 0, flags);
    k_gemv2<<<dim3(NND / 4, 1), 256, 0, stream>>>(x2, uo1, uo2, Wh1o, Wh2o, NND, F2, 0, 0, flags, 0);
    // output fused attention+projection (IBLK=32, R20-proven) -> ofull (sigmoid): grid (96, 4, 1)
    k_fatt7<<<dim3(96, 4, 1), 256, 0, stream>>>(Wh1o, Wh2o, 0, adjbits, Zbuf,
                                                ofull, DD, 0, 1);
    k_gather<<<(64 * DD + 255) / 256, 256, 0, stream>>>(ofull, tid, d_out, flags);
}